// Round 9
// baseline (2997.438 us; speedup 1.0000x reference)
//
#include <hip/hip_runtime.h>
#include <stdint.h>

// ---------------------------------------------------------------------------
// MarketScoringUnit: LSTM(B=128,T=512,H=512) + attention + (mu, sigma) head.
// Round 19: single-mega design. ALL pre-phase work moves into mega as roles:
//  - ti0 xg GEMM re-tiled 4b x 32t (fp32 A/B staged with in-register RNE
//    convert, bit-identical); lstm guards at t in {0,32,64,96} on per-block
//    done counters (proven release/acquire pattern, fired 4x total).
//  - conv role (x_bf/Wih_bf/U1a/U1b/U2b); ti123 + helpers acquire-guard on
//    conv-done. ti123 stays bf16 (R14-identical traffic in the lstm window).
//  - lstm Wreg loaded from fp32 Whh (preamble only); bias = bih+bhh inline.
// Launch chain: memset -> mega -> attn_out (was 5 dispatches; ~200us of
// unaccounted inter-dispatch overhead is the target).
// lstm inner loop remains R14 VERBATIM (frozen; 4 prior edit attempts failed).
// ---------------------------------------------------------------------------

using short8  = __attribute__((ext_vector_type(8))) short;   // 8 bf16 (4 VGPRs)
using short4v = __attribute__((ext_vector_type(4))) short;
using floatx4 = __attribute__((ext_vector_type(4))) float;

#define MFMA16(a, b, c) __builtin_amdgcn_mfma_f32_16x16x32_bf16((a), (b), (c), 0, 0, 0)

__device__ __forceinline__ unsigned short f2b(float f) {
    unsigned u = __float_as_uint(f);
    u += 0x7FFFu + ((u >> 16) & 1u);           // RNE
    return (unsigned short)(u >> 16);
}
__device__ __forceinline__ float b2f(unsigned short h) {
    return __uint_as_float(((unsigned)h) << 16);
}
__device__ __forceinline__ float sigm(float x) { return 1.0f / (1.0f + __expf(-x)); }
__device__ __forceinline__ float tanh_(float x) { return 1.0f - 2.0f / (__expf(2.0f * x) + 1.0f); }

// load 8 consecutive fp32, convert to bf16x8 in-register (bit-identical to
// converting through memory).
__device__ __forceinline__ short8 cvt8(const float* __restrict__ p) {
    float4 v0 = *(const float4*)p;
    float4 v1 = *(const float4*)(p + 4);
    short8 o;
    o[0] = (short)f2b(v0.x); o[1] = (short)f2b(v0.y);
    o[2] = (short)f2b(v0.z); o[3] = (short)f2b(v0.w);
    o[4] = (short)f2b(v1.x); o[5] = (short)f2b(v1.y);
    o[6] = (short)f2b(v1.z); o[7] = (short)f2b(v1.w);
    return o;
}

#define TI0_WGS   2048
#define CONV_WGS  512
#define TI123_WGS 6144
#define ATTN_WGS  2432

// ---------------------------------------------------------------------------
// gemm_core_bf: bf16 inputs, contiguous 128-row m-tile, scatter into xg
// layout [t][jg][b][c]; bias computed inline from bih+bhh. (R14 gemm_core,
// mode==1 path only.)
// ---------------------------------------------------------------------------
__device__ __forceinline__ void gemm_core_bf(
    const unsigned short* __restrict__ A, long long lda,
    const unsigned short* __restrict__ Bm,
    unsigned short* __restrict__ C,
    const float* __restrict__ bih, const float* __restrict__ bhh,
    int m0, int n0, int tid, unsigned short* sbuf)
{
    unsigned short* At = sbuf;
    unsigned short* Bt = sbuf + 128 * 72;
    unsigned short* Ct = sbuf;  // alias, used after final sync

    const int wv = tid >> 6, lane = tid & 63, l15 = lane & 15, q = lane >> 4;
    const int wm = wv & 1, wn = wv >> 1;

    floatx4 acc[4][4];
    for (int i = 0; i < 4; i++)
        for (int j = 0; j < 4; j++) acc[i][j] = (floatx4){0.f, 0.f, 0.f, 0.f};

    for (int k0 = 0; k0 < 512; k0 += 64) {
        for (int p = 0; p < 4; p++) {
            int idx = tid + p * 256;
            int row = idx >> 3, ch = idx & 7;
            *(short8*)&At[row * 72 + ch * 8] =
                *(const short8*)&A[(long long)(m0 + row) * lda + k0 + ch * 8];
            *(short8*)&Bt[row * 72 + ch * 8] =
                *(const short8*)&Bm[(long long)(n0 + row) * 512 + k0 + ch * 8];
        }
        __syncthreads();
        for (int ks = 0; ks < 64; ks += 32) {
            short8 af[4], bfv[4];
            for (int mi = 0; mi < 4; mi++)
                af[mi] = *(const short8*)&At[(wm * 64 + mi * 16 + l15) * 72 + ks + q * 8];
            for (int ni = 0; ni < 4; ni++)
                bfv[ni] = *(const short8*)&Bt[(wn * 64 + ni * 16 + l15) * 72 + ks + q * 8];
            for (int mi = 0; mi < 4; mi++)
                for (int ni = 0; ni < 4; ni++)
                    acc[mi][ni] = MFMA16(af[mi], bfv[ni], acc[mi][ni]);
        }
        __syncthreads();
    }

    float bv[4];
    for (int ni = 0; ni < 4; ni++) {
        int nn = n0 + wn * 64 + ni * 16 + l15;
        bv[ni] = bih[nn] + bhh[nn];
    }

    for (int mi = 0; mi < 4; mi++)
        for (int ni = 0; ni < 4; ni++)
            for (int r = 0; r < 4; r++)
                Ct[(wm * 64 + mi * 16 + q * 4 + r) * 128 + wn * 64 + ni * 16 + l15] =
                    f2b(acc[mi][ni][r] + bv[ni]);
    __syncthreads();

    const int tt0 = m0 & 511, bglob = m0 >> 9;
    for (int p = 0; p < 8; p++) {
        int idx = tid + p * 256;
        int row = idx >> 4, ch = idx & 15;
        int n = n0 + ch * 8;
        int gate = n >> 9, jg = (n >> 4) & 31, c0 = gate * 16 + (n & 15);
        long long dst = (((long long)(tt0 + row) * 32 + jg) * 128 + bglob) * 64 + c0;
        *(short8*)&C[dst] = *(const short8*)&Ct[row * 128 + ch * 8];
    }
}

// ---------------------------------------------------------------------------
// gemm_core_ti0: 4-batch x 32-t m-tile, A/B staged from fp32 x/Wih with
// in-register convert (bit-identical). Tiles of one 32-t block complete
// together -> per-block done counter unblocks the lstm.
// ---------------------------------------------------------------------------
__device__ __forceinline__ void gemm_core_ti0(
    const float* __restrict__ x,      // (128,512,512) fp32
    const float* __restrict__ Wih,    // (2048,512) fp32
    unsigned short* __restrict__ C,
    const float* __restrict__ bih, const float* __restrict__ bhh,
    int b0, int t0, int n0, int tid, unsigned short* sbuf)
{
    unsigned short* At = sbuf;
    unsigned short* Bt = sbuf + 128 * 72;
    unsigned short* Ct = sbuf;  // alias, used after final sync

    const int wv = tid >> 6, lane = tid & 63, l15 = lane & 15, q = lane >> 4;
    const int wm = wv & 1, wn = wv >> 1;

    floatx4 acc[4][4];
    for (int i = 0; i < 4; i++)
        for (int j = 0; j < 4; j++) acc[i][j] = (floatx4){0.f, 0.f, 0.f, 0.f};

    for (int k0 = 0; k0 < 512; k0 += 64) {
        for (int p = 0; p < 4; p++) {
            int idx = tid + p * 256;
            int row = idx >> 3, ch = idx & 7;
            int bq = row >> 5, tq = row & 31;
            *(short8*)&At[row * 72 + ch * 8] =
                cvt8(&x[((long long)(b0 + bq) * 512 + t0 + tq) * 512 + k0 + ch * 8]);
            *(short8*)&Bt[row * 72 + ch * 8] =
                cvt8(&Wih[(long long)(n0 + row) * 512 + k0 + ch * 8]);
        }
        __syncthreads();
        for (int ks = 0; ks < 64; ks += 32) {
            short8 af[4], bfv[4];
            for (int mi = 0; mi < 4; mi++)
                af[mi] = *(const short8*)&At[(wm * 64 + mi * 16 + l15) * 72 + ks + q * 8];
            for (int ni = 0; ni < 4; ni++)
                bfv[ni] = *(const short8*)&Bt[(wn * 64 + ni * 16 + l15) * 72 + ks + q * 8];
            for (int mi = 0; mi < 4; mi++)
                for (int ni = 0; ni < 4; ni++)
                    acc[mi][ni] = MFMA16(af[mi], bfv[ni], acc[mi][ni]);
        }
        __syncthreads();
    }

    float bv[4];
    for (int ni = 0; ni < 4; ni++) {
        int nn = n0 + wn * 64 + ni * 16 + l15;
        bv[ni] = bih[nn] + bhh[nn];
    }

    for (int mi = 0; mi < 4; mi++)
        for (int ni = 0; ni < 4; ni++)
            for (int r = 0; r < 4; r++)
                Ct[(wm * 64 + mi * 16 + q * 4 + r) * 128 + wn * 64 + ni * 16 + l15] =
                    f2b(acc[mi][ni][r] + bv[ni]);
    __syncthreads();

    for (int p = 0; p < 8; p++) {
        int idx = tid + p * 256;
        int row = idx >> 4, ch = idx & 15;
        int bq = row >> 5, tq = row & 31;
        int n = n0 + ch * 8;
        int gate = n >> 9, jg = (n >> 4) & 31, c0 = gate * 16 + (n & 15);
        long long dst = (((long long)(t0 + tq) * 32 + jg) * 128 + (b0 + bq)) * 64 + c0;
        *(short8*)&C[dst] = *(const short8*)&Ct[row * 128 + ch * 8];
    }
}

// ---------------------------------------------------------------------------
// attn helper body: a[b, t0..t0+32, nBase..nBase+NNI*64) = h@U1a^T + x@U2^T
// (fp32 into consumed xg slots). NNI=8: full 512-n tile; NNI=2: quarter tile
// (last t-tile only). Guards: lstm progress (relaxed) + conv done (acquire).
// ---------------------------------------------------------------------------
template<int NNI>
__device__ __forceinline__ void attn_helper_body(
    const unsigned short* __restrict__ h_all,
    const unsigned short* __restrict__ x_bf,
    const unsigned short* __restrict__ U1a,
    const unsigned short* __restrict__ U2b,
    unsigned short* __restrict__ xg_out,
    int* __restrict__ syncp,
    int b, int t0, int nBase, int tid, char* smem)
{
    const int bg = b >> 4;
    if (tid < 8) {
        while (__hip_atomic_load(&syncp[16 + (bg * 8 + tid) * 16],
                                 __ATOMIC_RELAXED,
                                 __HIP_MEMORY_SCOPE_AGENT) < t0 + 32)
            __builtin_amdgcn_s_sleep(8);
    } else if (tid == 8) {
        while (__hip_atomic_load(&syncp[8], __ATOMIC_ACQUIRE,
                                 __HIP_MEMORY_SCOPE_AGENT) < CONV_WGS)
            __builtin_amdgcn_s_sleep(8);
    }
    __syncthreads();

    unsigned short* Bt2 = (unsigned short*)smem;                      // NNI*64 x 40
    unsigned short* At2 = (unsigned short*)smem + (NNI * 64) * 40;    // 32 x 40

    const int wv = tid >> 6, lane = tid & 63, l15 = lane & 15, q = lane >> 4;

    floatx4 acc[2][NNI];
    #pragma unroll
    for (int mi = 0; mi < 2; mi++)
        #pragma unroll
        for (int ni = 0; ni < NNI; ni++) acc[mi][ni] = (floatx4){0.f, 0.f, 0.f, 0.f};

    for (int it = 0; it < 32; it++) {
        const int phase = it >> 4, kk = (it & 15) * 32;
        const unsigned short* Bsrc = phase ? U2b : U1a;
        __syncthreads();
        #pragma unroll
        for (int pp = 0; pp < NNI; pp++) {
            int idx = tid + pp * 256;
            int row = idx >> 2, ch = idx & 3;
            *(short8*)&Bt2[row * 40 + ch * 8] =
                *(const short8*)&Bsrc[(long long)(nBase + row) * 512 + kk + ch * 8];
        }
        if (tid < 128) {
            int row = tid >> 2, ch = tid & 3;
            if (phase == 0) {
                unsigned long long* p = (unsigned long long*)
                    &h_all[((long long)b * 512 + t0 + row) * 512 + kk + ch * 8];
                unsigned long long lo = __hip_atomic_load(p, __ATOMIC_RELAXED,
                                                          __HIP_MEMORY_SCOPE_AGENT);
                unsigned long long hi = __hip_atomic_load(p + 1, __ATOMIC_RELAXED,
                                                          __HIP_MEMORY_SCOPE_AGENT);
                unsigned long long* d = (unsigned long long*)&At2[row * 40 + ch * 8];
                d[0] = lo; d[1] = hi;
            } else {
                *(short8*)&At2[row * 40 + ch * 8] =
                    *(const short8*)&x_bf[((long long)b * 512 + t0 + row) * 512 + kk + ch * 8];
            }
        }
        __syncthreads();
        short8 af0 = *(const short8*)&At2[(l15) * 40 + q * 8];
        short8 af1 = *(const short8*)&At2[(16 + l15) * 40 + q * 8];
        #pragma unroll
        for (int ni = 0; ni < NNI; ni++) {
            short8 bfv = *(const short8*)&Bt2[(wv * (NNI * 16) + ni * 16 + l15) * 40 + q * 8];
            acc[0][ni] = MFMA16(af0, bfv, acc[0][ni]);
            acc[1][ni] = MFMA16(af1, bfv, acc[1][ni]);
        }
    }
    // write fp32 a[t,b,n] into the consumed xg slot (t*32+(n>>5))*128+b
    #pragma unroll
    for (int mi = 0; mi < 2; mi++)
        #pragma unroll
        for (int ni = 0; ni < NNI; ni++) {
            const int n = nBase + wv * (NNI * 16) + ni * 16 + l15;
            #pragma unroll
            for (int r = 0; r < 4; r++) {
                const int t = t0 + mi * 16 + q * 4 + r;
                float* slot = (float*)&xg_out[(((long long)t * 32 + (n >> 5)) * 128 + b) * 64];
                slot[n & 31] = acc[mi][ni][r];
            }
        }
}

// ---------------------------------------------------------------------------
// mega roles by blockIdx:
//   [0,64)          lstm (R14-verbatim loop; Wreg from fp32 Whh; guards at
//                   t in {0,32,64,96} on ti0 block counters, t==128 on ti123)
//   [64,2112)       ti0 tiles (4b x 32t, fp32-staged), done -> syncp[1+tb]
//   [2112,2624)     conv: x_bf/Wih_bf/U1a/U1b/U2b, done -> syncp[8]
//   [2624,8768)     ti123 tiles (bf16, guarded on conv), done -> syncp[0]
//   [8768,11200)    attn helpers (1920 full + 512 quarter)
// LDS = 86016 for every role -> 1 WG/CU (lstm isolation, R13/R14-proven).
// ---------------------------------------------------------------------------
__global__ __launch_bounds__(256, 1) void mega(
    const float* __restrict__ x,       // (128,512,512) fp32
    const float* __restrict__ Wih,     // (2048,512) fp32
    const float* __restrict__ Whh,     // (2048,512) fp32
    const float* __restrict__ bih, const float* __restrict__ bhh,
    const float* __restrict__ U1, const float* __restrict__ U2,
    unsigned short* __restrict__ x_bf,
    unsigned short* __restrict__ Wih_bf,
    unsigned short* __restrict__ U1a, unsigned short* __restrict__ U1b,
    unsigned short* __restrict__ U2b,
    unsigned short* __restrict__ xg,     // xg / a[] slots (in+out)
    unsigned short* __restrict__ h_all,  // [b][t][h]
    unsigned int* __restrict__ ring,     // [2][128][512] tagged words
    int* __restrict__ syncp)
{
    __shared__ __align__(16) char smem[86016];   // forces 1 WG/CU for all roles

    const int tid = threadIdx.x;
    const int bid = (int)blockIdx.x;

    if (bid >= 64 && bid < 64 + TI0_WGS) {
        // -------- ti0 role: xg for t<128, 4b x 32t tiles, fp32-staged ------
        int g = bid - 64;
        int tb = g >> 9;               // 0..3 (t-block), ascending dispatch
        int r = g & 511;
        int b0 = (r & 31) * 4;
        int n0 = (r >> 5) * 128;
        gemm_core_ti0(x, Wih, xg, bih, bhh, b0, tb * 32, n0, tid,
                      (unsigned short*)smem);
        __syncthreads();               // all waves' stores drained
        if (tid == 0)
            __hip_atomic_fetch_add(&syncp[1 + tb], 1, __ATOMIC_RELEASE,
                                   __HIP_MEMORY_SCOPE_AGENT);
        return;
    }

    if (bid >= 64 + TI0_WGS && bid < 64 + TI0_WGS + CONV_WGS) {
        // -------- conv role: bf16 conversions for ti123 / helpers ----------
        const long long NX4 = 33554432LL / 4;  // x as float4
        const long long NREST = 1048576LL + 524288LL + 262144LL;
        const long long total = NX4 + NREST;
        const int cb = bid - (64 + TI0_WGS);
        for (long long u = (long long)cb * 256 + tid; u < total;
             u += (long long)CONV_WGS * 256) {
            if (u < NX4) {
                float4 v = ((const float4*)x)[u];
                short4v o;
                o[0] = (short)f2b(v.x); o[1] = (short)f2b(v.y);
                o[2] = (short)f2b(v.z); o[3] = (short)f2b(v.w);
                *(short4v*)&x_bf[u * 4] = o;
            } else {
                long long i = u - NX4;
                if (i < 1048576) { Wih_bf[i] = f2b(Wih[i]); continue; }
                i -= 1048576;
                if (i < 524288) {
                    int row = (int)(i >> 10), col = (int)(i & 1023);
                    if (col < 512) U1a[row * 512 + col] = f2b(U1[i]);
                    else           U1b[row * 512 + (col - 512)] = f2b(U1[i]);
                    continue;
                }
                i -= 524288;
                U2b[i] = f2b(U2[i]);
            }
        }
        __syncthreads();               // stores drained
        if (tid == 0)
            __hip_atomic_fetch_add(&syncp[8], 1, __ATOMIC_RELEASE,
                                   __HIP_MEMORY_SCOPE_AGENT);
        return;
    }

    if (bid >= 64 + TI0_WGS + CONV_WGS &&
        bid < 64 + TI0_WGS + CONV_WGS + TI123_WGS) {
        // -------- ti123 role: xg for t in [128,512), bf16 (R14 tiles) ------
        if (tid == 0) {
            while (__hip_atomic_load(&syncp[8], __ATOMIC_ACQUIRE,
                                     __HIP_MEMORY_SCOPE_AGENT) < CONV_WGS)
                __builtin_amdgcn_s_sleep(8);
        }
        __syncthreads();
        int g = bid - (64 + TI0_WGS + CONV_WGS);
        int b = g & 127;
        int r = g >> 7;                // 0..47
        int ti = 1 + (r % 3);          // 1..3
        int n = r / 3;                 // 0..15
        gemm_core_bf(x_bf, 512, Wih_bf, xg, bih, bhh,
                     b * 512 + ti * 128, n * 128, tid, (unsigned short*)smem);
        __syncthreads();               // all waves' stores drained
        if (tid == 0)
            __hip_atomic_fetch_add(&syncp[0], 1, __ATOMIC_RELEASE,
                                   __HIP_MEMORY_SCOPE_AGENT);
        return;
    }

    if (bid >= 64 + TI0_WGS + CONV_WGS + TI123_WGS) {
        // -------- attn helper role: a = h@U1a^T + x@U2^T -------------------
        const int g = bid - (64 + TI0_WGS + CONV_WGS + TI123_WGS);
        if (g < 1920) {
            attn_helper_body<8>(h_all, x_bf, U1a, U2b, xg, syncp,
                                g & 127, (g >> 7) * 32, 0, tid, smem);
        } else {
            const int j = g - 1920;
            attn_helper_body<2>(h_all, x_bf, U1a, U2b, xg, syncp,
                                j & 127, 480, (j >> 7) * 128, tid, smem);
        }
        return;
    }

    // ---------------- lstm role (R14 VERBATIM inner loop) ----------------
    unsigned int (*At)[16 * 264] = (unsigned int (*)[16 * 264])smem;

    const int wv = tid >> 6, lane = tid & 63, l15 = lane & 15, q = lane >> 4;
    const int bg = bid >> 3, jgb = bid & 7;
    const int b0 = bg * 16;
    const int jg32 = jgb * 4 + wv;            // 16-hid group of this wave
    const int hid = jg32 * 16 + l15;          // this lane's hidden index

    // W_hh B-frags from fp32 Whh (in-register RNE convert, bit-identical):
    // Wreg[ct][kk], row = ct*512 + hid, k = kk*32 + q*8
    short8 Wreg[4][16];
    #pragma unroll
    for (int ct = 0; ct < 4; ct++)
        #pragma unroll
        for (int kk = 0; kk < 16; kk++)
            Wreg[ct][kk] = cvt8(&Whh[(long long)(ct * 512 + hid) * 512 + kk * 32 + q * 8]);

    float cst[4] = {0.f, 0.f, 0.f, 0.f};

    for (int t = 0; t < 512; t++) {
        // guards: ti0 block counters at t in {0,32,64,96}; ti123 at t==128
        if ((t & 31) == 0 && t <= 128) {
            if (tid == 0) {
                if (t < 128) {
                    while (__hip_atomic_load(&syncp[1 + (t >> 5)], __ATOMIC_ACQUIRE,
                                             __HIP_MEMORY_SCOPE_AGENT) < 512)
                        __builtin_amdgcn_s_sleep(8);
                } else {
                    while (__hip_atomic_load(&syncp[0], __ATOMIC_ACQUIRE,
                                             __HIP_MEMORY_SCOPE_AGENT) < TI123_WGS)
                        __builtin_amdgcn_s_sleep(8);
                }
            }
            __syncthreads();
        }
        // ---- prefetch xg: acc-init values, 16 scalar loads (pre-poll) ----
        const long long xbase = ((long long)(t * 32 + jg32) * 128 + b0) * 64;
        floatx4 acc[4];
        #pragma unroll
        for (int ct = 0; ct < 4; ct++)
            #pragma unroll
            for (int r = 0; r < 4; r++)
                acc[ct][r] = b2f(xg[xbase + (q * 4 + r) * 64 + ct * 16 + l15]);

        if (t > 0) {
            const unsigned want = (unsigned)(t - 1);
            const int sl = (t - 1) & 1;
            unsigned long long* rb = (unsigned long long*)
                (ring + sl * 65536 + b0 * 512);
            unsigned long long w[16];
            #pragma unroll
            for (int i = 0; i < 16; i++)
                w[i] = __hip_atomic_load(&rb[tid + i * 256], __ATOMIC_RELAXED,
                                         __HIP_MEMORY_SCOPE_AGENT);
            while (true) {
                unsigned bad = 0;
                #pragma unroll
                for (int i = 0; i < 16; i++) {
                    unsigned lo = (unsigned)(w[i] >> 16) & 0xFFFFu;
                    unsigned hi = (unsigned)(w[i] >> 48);
                    bad |= (lo ^ want) | (hi ^ want);
                }
                if (!bad) break;
                #pragma unroll
                for (int i = 0; i < 16; i++) {
                    unsigned lo = (unsigned)(w[i] >> 16) & 0xFFFFu;
                    unsigned hi = (unsigned)(w[i] >> 48);
                    if ((lo ^ want) | (hi ^ want))
                        w[i] = __hip_atomic_load(&rb[tid + i * 256], __ATOMIC_RELAXED,
                                                 __HIP_MEMORY_SCOPE_AGENT);
                }
            }
            // strip tags, pack two bf16 per LDS word
            unsigned int* dst = &At[sl][0];
            #pragma unroll
            for (int i = 0; i < 16; i++) {
                int idx = tid + i * 256;
                int row = idx >> 8, k = idx & 255;
                dst[row * 264 + k] =
                    (unsigned)(w[i] & 0xFFFFu) | ((unsigned)(w[i] >> 32) << 16);
            }
            __syncthreads();
            // MFMA: A = h tile (batch l15, K), B = Wreg; 4 chains (one/gate)
            const unsigned int* ap = &At[sl][l15 * 264 + q * 4];
            #pragma unroll
            for (int kk = 0; kk < 16; kk++) {
                short8 af = *(const short8*)(ap + kk * 16);
                acc[0] = MFMA16(af, Wreg[0][kk], acc[0]);
                acc[1] = MFMA16(af, Wreg[1][kk], acc[1]);
                acc[2] = MFMA16(af, Wreg[2][kk], acc[2]);
                acc[3] = MFMA16(af, Wreg[3][kk], acc[3]);
            }
        }
        // ---- pointwise: gates are in-lane (acc[0..3] = i,f,g,o) ----
        unsigned short hbv[4];
        #pragma unroll
        for (int r = 0; r < 4; r++) {
            float ig = sigm(acc[0][r]);
            float fg = sigm(acc[1][r]);
            float gv = tanh_(acc[2][r]);
            float og = sigm(acc[3][r]);
            cst[r] = fg * cst[r] + ig * gv;
            hbv[r] = f2b(og * tanh_(cst[r]));
        }
        // publish: ring first (latency-critical)
        #pragma unroll
        for (int r = 0; r < 4; r++) {
            const int b = b0 + q * 4 + r;
            __hip_atomic_store(&ring[(t & 1) * 65536 + b * 512 + hid],
                               ((unsigned)t << 16) | hbv[r], __ATOMIC_RELAXED,
                               __HIP_MEMORY_SCOPE_AGENT);
        }
        // h_all: agent-visible packed 4B atomic stores (pair hid, hid^1)
        // so shadow helpers' LLC-direct atomic loads always see fresh data.
        #pragma unroll
        for (int r = 0; r < 4; r++) {
            const int b = b0 + q * 4 + r;
            int o = __shfl_xor((int)hbv[r], 1);
            if (!(l15 & 1)) {
                unsigned v = (unsigned)hbv[r] | (((unsigned)(unsigned short)o) << 16);
                __hip_atomic_store(
                    (unsigned*)&h_all[(long long)b * 262144 + (long long)t * 512 + hid],
                    v, __ATOMIC_RELAXED, __HIP_MEMORY_SCOPE_AGENT);
            }
        }
        // progress word every 16 steps: barrier drains all waves' h stores
        // (agent-visible), so prog >= t+1 implies h[..t] readable by helpers.
        if ((t & 15) == 15) {
            __syncthreads();
            if (tid == 0)
                __hip_atomic_store(&syncp[16 + bid * 16], t + 1,
                                   __ATOMIC_RELAXED, __HIP_MEMORY_SCOPE_AGENT);
        }
    }
}

// ---------------------------------------------------------------------------
// attn_out: u1b = h_last@U1b^T (in-WG), e = Ve.tanh(a + u1b) (a from xg
// slots), softmax over T, context = alpha.h, head -> mu, sigma. 1 WG per b.
// ---------------------------------------------------------------------------
__global__ __launch_bounds__(256) void attn_out(
    const unsigned short* __restrict__ a_xg,  // fp32 a[] in xg slot layout
    const unsigned short* __restrict__ h_all,
    const unsigned short* __restrict__ U1b,   // bf16 (512,512)
    const float* __restrict__ Ve,
    const float* __restrict__ Wout, const float* __restrict__ bout,
    float* __restrict__ outp)
{
    __shared__ float hl[512];
    __shared__ float u1s[512];
    __shared__ float se[512];
    __shared__ float sm[512];
    __shared__ float red[8];
    const int b = blockIdx.x, tid = threadIdx.x;
    const int wv = tid >> 6, lane = tid & 63;

    // ---- phase 0: u1b[b,n] = sum_k h_last[b,k] * U1b[n,k] ----
    {
        unsigned v = ((const unsigned*)(h_all + (long long)b * 262144 + 511LL * 512))[tid];
        hl[2 * tid]     = b2f((unsigned short)(v & 0xFFFFu));
        hl[2 * tid + 1] = b2f((unsigned short)(v >> 16));
    }
    __syncthreads();
    #pragma unroll
    for (int rr = 0; rr < 2; rr++) {
        const int n = tid + rr * 256;
        const unsigned short* up = &U1b[(long long)n * 512];
        float s = 0.f;
        for (int k = 0; k < 512; k += 8) {
            short8 v8 = *(const short8*)&up[k];
            #pragma unroll
            for (int j = 0; j < 8; j++)
                s += hl[k + j] * b2f((unsigned short)v8[j]);
        }
        u1s[n] = s;
    }
    __syncthreads();

    // ---- phase 1: e[t] = sum_n Ve[n] * tanh(a[t,n] + u1b[b,n]) ----
    const int n0 = lane * 8;
    float ve[8], ub[8];
    #pragma unroll
    for (int j = 0; j < 8; j++) {
        ve[j] = Ve[n0 + j];
        ub[j] = u1s[n0 + j];
    }
    for (int it = 0; it < 64; it++) {
        const int t = it * 8 + wv * 2;
        const float* s0p = (const float*)
            &a_xg[(((long long)t * 32 + (n0 >> 5)) * 128 + b) * 64];
        const float* s1p = (const float*)
            &a_xg[(((long long)(t + 1) * 32 + (n0 >> 5)) * 128 + b) * 64];
        float4 a0 = *(const float4*)&s0p[n0 & 31];
        float4 a1 = *(const float4*)&s0p[(n0 & 31) + 4];
        float4 a2 = *(const float4*)&s1p[n0 & 31];
        float4 a3 = *(const float4*)&s1p[(n0 & 31) + 4];
        float s0 = ve[0] * tanh_(a0.x + ub[0]) + ve[1] * tanh_(a0.y + ub[1])
                 + ve[2] * tanh_(a0.z + ub[2]) + ve[3] * tanh_(a0.w + ub[3])
                 + ve[4] * tanh_(a1.x + ub[4]) + ve[5] * tanh_(a1.y + ub[5])
                 + ve[6] * tanh_(a1.z + ub[6]) + ve[7] * tanh_(a1.w + ub[7]);
        float s1 = ve[0] * tanh_(a2.x + ub[0]) + ve[1] * tanh_(a2.y + ub[1])
                 + ve[2] * tanh_(a2.z + ub[2]) + ve[3] * tanh_(a2.w + ub[3])
                 + ve[4] * tanh_(a3.x + ub[4]) + ve[5] * tanh_(a3.y + ub[5])
                 + ve[6] * tanh_(a3.z + ub[6]) + ve[7] * tanh_(a3.w + ub[7]);
        #pragma unroll
        for (int off = 1; off <= 32; off <<= 1) {
            s0 += __shfl_xor(s0, off);
            s1 += __shfl_xor(s1, off);
        }
        if (lane == 0) { se[t] = s0; se[t + 1] = s1; }
    }
    __syncthreads();

    // ---- phase 2: softmax over T ----
    float e0 = se[tid], e1 = se[256 + tid];
    float mx = fmaxf(e0, e1);
    for (int off = 32; off; off >>= 1) mx = fmaxf(mx, __shfl_xor(mx, off));
    if (lane == 0) red[wv] = mx;
    __syncthreads();
    mx = fmaxf(fmaxf(red[0], red[1]), fmaxf(red[2], red[3]));

    float s0 = __expf(e0 - mx), s1 = __expf(e1 - mx);
    sm[tid] = s0; sm[256 + tid] = s1;
    float ss = s0 + s1;
    for (int off = 32; off; off >>= 1) ss += __shfl_xor(ss, off);
    if (lane == 0) red[4 + wv] = ss;
    __syncthreads();
    float inv = 1.0f / (red[4] + red[5] + red[6] + red[7]);

    // ---- phase 3: context = alpha.h, head ----
    const unsigned int* hp = (const unsigned int*)(h_all + (long long)b * 262144);
    float a0 = 0.f, a1 = 0.f;
    for (int t = 0; t < 512; t += 4) {
        #pragma unroll
        for (int j = 0; j < 4; j++) {
            float al = sm[t + j];
            unsigned v = hp[(t + j) * 256 + tid];
            a0 += al * b2f((unsigned short)(v & 0xFFFFu));
            a1 += al * b2f((unsigned short)(v >> 16));
        }
    }
    a0 *= inv; a1 *= inv;

    float q0 = a0 * Wout[2 * tid] + a1 * Wout[2 * tid + 1];
    float q1 = a0 * Wout[512 + 2 * tid] + a1 * Wout[512 + 2 * tid + 1];
    for (int off = 32; off; off >>= 1) { q0 += __shfl_xor(q0, off); q1 += __shfl_xor(q1, off); }
    __syncthreads();  // red reuse
    if (lane == 0) { red[wv] = q0; red[4 + wv] = q1; }
    __syncthreads();
    if (tid == 0) {
        float P0 = red[0] + red[1] + red[2] + red[3] + bout[0];
        float P1 = red[4] + red[5] + red[6] + red[7] + bout[1];
        outp[b] = P0;
        float sp = (P1 > 15.0f) ? P1 : log1pf(__expf(P1));
        outp[128 + b] = sp + 1e-5f;
    }
}

// ---------------------------------------------------------------------------
extern "C" void kernel_launch(void* const* d_in, const int* in_sizes, int n_in,
                              void* d_out, int out_size, void* d_ws, size_t ws_size,
                              hipStream_t stream)
{
    const float* x    = (const float*)d_in[0];
    const float* Wih  = (const float*)d_in[1];
    const float* Whh  = (const float*)d_in[2];
    const float* bih  = (const float*)d_in[3];
    const float* bhh  = (const float*)d_in[4];
    const float* Ve   = (const float*)d_in[5];
    const float* U1   = (const float*)d_in[6];
    const float* U2   = (const float*)d_in[7];
    const float* Wout = (const float*)d_in[8];
    const float* bout = (const float*)d_in[9];
    float* out = (float*)d_out;

    char* ws = (char*)d_ws;
    size_t off = 0;
    auto alloc = [&](size_t bytes) -> void* {
        void* p = ws + off;
        off += (bytes + 255) & ~(size_t)255;
        return p;
    };
    unsigned short* x_bf   = (unsigned short*)alloc(33554432ull * 2);
    unsigned short* Wih_bf = (unsigned short*)alloc(1048576ull * 2);
    unsigned short* U1a    = (unsigned short*)alloc(262144ull * 2);
    unsigned short* U1b    = (unsigned short*)alloc(262144ull * 2);
    unsigned short* U2b    = (unsigned short*)alloc(262144ull * 2);
    unsigned short* xg     = (unsigned short*)alloc(134217728ull * 2);
    unsigned short* h_all  = (unsigned short*)alloc(33554432ull * 2);
    unsigned int*   ring   = (unsigned int*)alloc(131072ull * 4);  // 2x128x512 tagged
    int*            syncp  = (int*)alloc(8192ull);
    // syncp: [0]=ti123 done; [1..4]=ti0 t-block done; [8]=conv done;
    //        [16+wg*16]=lstm progress
    if (off > ws_size) return;  // workspace too small: fail safe (no corruption)

    hipMemsetAsync(syncp, 0, 8192, stream);
    // single mega: 64 lstm + 2048 ti0 + 512 conv + 6144 ti123 + 2432 helpers
    mega<<<64 + TI0_WGS + CONV_WGS + TI123_WGS + ATTN_WGS, 256, 0, stream>>>(
        x, Wih, Whh, bih, bhh, U1, U2,
        x_bf, Wih_bf, U1a, U1b, U2b, xg, h_all, ring, syncp);
    attn_out<<<128, 256, 0, stream>>>(xg, h_all, U1b, Ve, Wout, bout, out);
}

// Round 10
// 2463.676 us; speedup vs baseline: 1.2167x; 1.2167x over previous
//
#include <hip/hip_runtime.h>
#include <stdint.h>

// ---------------------------------------------------------------------------
// MarketScoringUnit: LSTM(B=128,T=512,H=512) + attention + (mu, sigma) head.
// Round 20: full revert to R17 (best verified config: R14 structure + u1b
// fold + quarter-tile tail; 2561-2567us). R18/R19 pre-phase fusions both
// regressed (lstm codegen + in-window traffic). ONE zero-cost experiment:
// lstm bg/jgb derivation swapped (bg = bid&7, jgb = bid>>3) so each
// bg-group's 8 exchange partners share bid%8 -> same XCD under the observed
// round-robin dispatch map. Agent-scope ring protocol unchanged (correct
// under any placement); this is purely a locality heuristic on the dominant
// cross-WG poll roundtrip. Helper progress-poll index follows the remap.
// ---------------------------------------------------------------------------

using short8  = __attribute__((ext_vector_type(8))) short;   // 8 bf16 (4 VGPRs)
using short4v = __attribute__((ext_vector_type(4))) short;
using floatx4 = __attribute__((ext_vector_type(4))) float;

#define MFMA16(a, b, c) __builtin_amdgcn_mfma_f32_16x16x32_bf16((a), (b), (c), 0, 0, 0)

__device__ __forceinline__ unsigned short f2b(float f) {
    unsigned u = __float_as_uint(f);
    u += 0x7FFFu + ((u >> 16) & 1u);           // RNE
    return (unsigned short)(u >> 16);
}
__device__ __forceinline__ float b2f(unsigned short h) {
    return __uint_as_float(((unsigned)h) << 16);
}
__device__ __forceinline__ float sigm(float x) { return 1.0f / (1.0f + __expf(-x)); }
__device__ __forceinline__ float tanh_(float x) { return 1.0f - 2.0f / (__expf(2.0f * x) + 1.0f); }

// ---------------------------------------------------------------------------
// prep: fp32 -> bf16 conversions, U1 split into U1a/U1b, bias = b_ih + b_hh
// ---------------------------------------------------------------------------
__global__ __launch_bounds__(256) void prep(
    const float* __restrict__ x, const float* __restrict__ Wih, const float* __restrict__ Whh,
    const float* __restrict__ bih, const float* __restrict__ bhh,
    const float* __restrict__ U1, const float* __restrict__ U2,
    unsigned short* __restrict__ x_bf, unsigned short* __restrict__ Wih_bf,
    unsigned short* __restrict__ Whh_bf, unsigned short* __restrict__ U1a,
    unsigned short* __restrict__ U1b, unsigned short* __restrict__ U2b,
    float* __restrict__ bias)
{
    const long long NX4 = 33554432LL / 4;  // x as float4
    const long long NREST = 1048576LL + 1048576LL + 524288LL + 262144LL + 2048LL;
    const long long total = NX4 + NREST;
    for (long long u = (long long)blockIdx.x * 256 + threadIdx.x; u < total;
         u += (long long)gridDim.x * 256) {
        if (u < NX4) {
            float4 v = ((const float4*)x)[u];
            short4v o;
            o[0] = (short)f2b(v.x); o[1] = (short)f2b(v.y);
            o[2] = (short)f2b(v.z); o[3] = (short)f2b(v.w);
            *(short4v*)&x_bf[u * 4] = o;
        } else {
            long long i = u - NX4;
            if (i < 1048576) { Wih_bf[i] = f2b(Wih[i]); continue; }
            i -= 1048576;
            if (i < 1048576) { Whh_bf[i] = f2b(Whh[i]); continue; }
            i -= 1048576;
            if (i < 524288) {
                int row = (int)(i >> 10), col = (int)(i & 1023);
                if (col < 512) U1a[row * 512 + col] = f2b(U1[i]);
                else           U1b[row * 512 + (col - 512)] = f2b(U1[i]);
                continue;
            }
            i -= 524288;
            if (i < 262144) { U2b[i] = f2b(U2[i]); continue; }
            i -= 262144;
            bias[i] = bih[i] + bhh[i];
        }
    }
}

// ---------------------------------------------------------------------------
// gemm_core: C[m][n] = sum_k A[m][k]*B[n][k] (+bias[n]); bf16, fp32 acc.
// 128x128 tile, BK=64, 4 waves of 64x64. mode==1: scatter into xg layout
// [t][jg][b][c], c = gate*16+(n&15), jg=(n>>4)&31, gate=n>>9.
// ---------------------------------------------------------------------------
__device__ __forceinline__ void gemm_core(
    const unsigned short* __restrict__ A, long long lda,
    const unsigned short* __restrict__ Bm, long long ldb,
    unsigned short* __restrict__ C, long long ldc,
    const float* __restrict__ bias, int mode,
    int m0, int n0, int tid, unsigned short* sbuf)
{
    unsigned short* At = sbuf;
    unsigned short* Bt = sbuf + 128 * 72;
    unsigned short* Ct = sbuf;  // alias, used after final sync

    const int wv = tid >> 6, lane = tid & 63, l15 = lane & 15, q = lane >> 4;
    const int wm = wv & 1, wn = wv >> 1;

    floatx4 acc[4][4];
    for (int i = 0; i < 4; i++)
        for (int j = 0; j < 4; j++) acc[i][j] = (floatx4){0.f, 0.f, 0.f, 0.f};

    for (int k0 = 0; k0 < 512; k0 += 64) {
        for (int p = 0; p < 4; p++) {
            int idx = tid + p * 256;
            int row = idx >> 3, ch = idx & 7;
            *(short8*)&At[row * 72 + ch * 8] =
                *(const short8*)&A[(long long)(m0 + row) * lda + k0 + ch * 8];
            *(short8*)&Bt[row * 72 + ch * 8] =
                *(const short8*)&Bm[(long long)(n0 + row) * ldb + k0 + ch * 8];
        }
        __syncthreads();
        for (int ks = 0; ks < 64; ks += 32) {
            short8 af[4], bfv[4];
            for (int mi = 0; mi < 4; mi++)
                af[mi] = *(const short8*)&At[(wm * 64 + mi * 16 + l15) * 72 + ks + q * 8];
            for (int ni = 0; ni < 4; ni++)
                bfv[ni] = *(const short8*)&Bt[(wn * 64 + ni * 16 + l15) * 72 + ks + q * 8];
            for (int mi = 0; mi < 4; mi++)
                for (int ni = 0; ni < 4; ni++)
                    acc[mi][ni] = MFMA16(af[mi], bfv[ni], acc[mi][ni]);
        }
        __syncthreads();
    }

    float bv[4];
    for (int ni = 0; ni < 4; ni++)
        bv[ni] = bias ? bias[n0 + wn * 64 + ni * 16 + l15] : 0.0f;

    for (int mi = 0; mi < 4; mi++)
        for (int ni = 0; ni < 4; ni++)
            for (int r = 0; r < 4; r++)
                Ct[(wm * 64 + mi * 16 + q * 4 + r) * 128 + wn * 64 + ni * 16 + l15] =
                    f2b(acc[mi][ni][r] + bv[ni]);
    __syncthreads();

    const int tt0 = m0 & 511, bglob = m0 >> 9;
    for (int p = 0; p < 8; p++) {
        int idx = tid + p * 256;
        int row = idx >> 4, ch = idx & 15;
        if (mode) {
            int n = n0 + ch * 8;
            int gate = n >> 9, jg = (n >> 4) & 31, c0 = gate * 16 + (n & 15);
            long long dst = (((long long)(tt0 + row) * 32 + jg) * 128 + bglob) * 64 + c0;
            *(short8*)&C[dst] = *(const short8*)&Ct[row * 128 + ch * 8];
        } else {
            *(short8*)&C[(long long)(m0 + row) * ldc + n0 + ch * 8] =
                *(const short8*)&Ct[row * 128 + ch * 8];
        }
    }
}

__global__ __launch_bounds__(256) void gemm_bt(
    const unsigned short* __restrict__ A, long long lda,
    const unsigned short* __restrict__ Bm, long long ldb,
    unsigned short* __restrict__ C, long long ldc,
    const float* __restrict__ bias, int mode, int mmul)
{
    __shared__ __align__(16) unsigned short sbuf[2 * 128 * 72];
    gemm_core(A, lda, Bm, ldb, C, ldc, bias, mode,
              blockIdx.x * mmul, blockIdx.y * 128, threadIdx.x, sbuf);
}

// ---------------------------------------------------------------------------
// attn helper body: a[b, t0..t0+32, nBase..nBase+NNI*64) = h@U1a^T + x@U2^T
// (fp32 into consumed xg slots). NNI=8: full 512-n tile; NNI=2: 128-n
// quarter tile (last t-tile only, to cut the post-lstm tail 4x).
// Progress words live at syncp[16 + (jgb*8 + bg)*16] (XCD-grouped remap).
// ---------------------------------------------------------------------------
template<int NNI>
__device__ __forceinline__ void attn_helper_body(
    const unsigned short* __restrict__ h_all,
    const unsigned short* __restrict__ x_bf,
    const unsigned short* __restrict__ U1a,
    const unsigned short* __restrict__ U2b,
    unsigned short* __restrict__ xg_out,
    int* __restrict__ syncp,
    int b, int t0, int nBase, int tid, char* smem)
{
    const int bg = b >> 4;
    if (tid < 8) {
        // producer WG for (bg, jgb=tid) has bid = tid*8 + bg (remapped)
        while (__hip_atomic_load(&syncp[16 + (tid * 8 + bg) * 16],
                                 __ATOMIC_RELAXED,
                                 __HIP_MEMORY_SCOPE_AGENT) < t0 + 32)
            __builtin_amdgcn_s_sleep(8);
    }
    __syncthreads();

    unsigned short* Bt2 = (unsigned short*)smem;                      // NNI*64 x 40
    unsigned short* At2 = (unsigned short*)smem + (NNI * 64) * 40;    // 32 x 40

    const int wv = tid >> 6, lane = tid & 63, l15 = lane & 15, q = lane >> 4;

    floatx4 acc[2][NNI];
    #pragma unroll
    for (int mi = 0; mi < 2; mi++)
        #pragma unroll
        for (int ni = 0; ni < NNI; ni++) acc[mi][ni] = (floatx4){0.f, 0.f, 0.f, 0.f};

    for (int it = 0; it < 32; it++) {
        const int phase = it >> 4, kk = (it & 15) * 32;
        const unsigned short* Bsrc = phase ? U2b : U1a;
        __syncthreads();
        #pragma unroll
        for (int pp = 0; pp < NNI; pp++) {
            int idx = tid + pp * 256;
            int row = idx >> 2, ch = idx & 3;
            *(short8*)&Bt2[row * 40 + ch * 8] =
                *(const short8*)&Bsrc[(long long)(nBase + row) * 512 + kk + ch * 8];
        }
        if (tid < 128) {
            int row = tid >> 2, ch = tid & 3;
            if (phase == 0) {
                unsigned long long* p = (unsigned long long*)
                    &h_all[((long long)b * 512 + t0 + row) * 512 + kk + ch * 8];
                unsigned long long lo = __hip_atomic_load(p, __ATOMIC_RELAXED,
                                                          __HIP_MEMORY_SCOPE_AGENT);
                unsigned long long hi = __hip_atomic_load(p + 1, __ATOMIC_RELAXED,
                                                          __HIP_MEMORY_SCOPE_AGENT);
                unsigned long long* d = (unsigned long long*)&At2[row * 40 + ch * 8];
                d[0] = lo; d[1] = hi;
            } else {
                *(short8*)&At2[row * 40 + ch * 8] =
                    *(const short8*)&x_bf[((long long)b * 512 + t0 + row) * 512 + kk + ch * 8];
            }
        }
        __syncthreads();
        short8 af0 = *(const short8*)&At2[(l15) * 40 + q * 8];
        short8 af1 = *(const short8*)&At2[(16 + l15) * 40 + q * 8];
        #pragma unroll
        for (int ni = 0; ni < NNI; ni++) {
            short8 bfv = *(const short8*)&Bt2[(wv * (NNI * 16) + ni * 16 + l15) * 40 + q * 8];
            acc[0][ni] = MFMA16(af0, bfv, acc[0][ni]);
            acc[1][ni] = MFMA16(af1, bfv, acc[1][ni]);
        }
    }
    // write fp32 a[t,b,n] into the consumed xg slot (t*32+(n>>5))*128+b
    #pragma unroll
    for (int mi = 0; mi < 2; mi++)
        #pragma unroll
        for (int ni = 0; ni < NNI; ni++) {
            const int n = nBase + wv * (NNI * 16) + ni * 16 + l15;
            #pragma unroll
            for (int r = 0; r < 4; r++) {
                const int t = t0 + mi * 16 + q * 4 + r;
                float* slot = (float*)&xg_out[(((long long)t * 32 + (n >> 5)) * 128 + b) * 64];
                slot[n & 31] = acc[mi][ni][r];
            }
        }
}

// ---------------------------------------------------------------------------
// mega: blockIdx < 64            -> lstm recurrence (R14-verbatim loop;
//                                   bg/jgb derivation XCD-grouped: bg=bid&7)
//       64 <= blockIdx < 64+6144 -> xg GEMM for t in [128,512) (R14 verbatim)
//       blockIdx >= 64+6144      -> attn helpers (1920 full + 512 quarter)
// LDS = 86016 for every role -> 1 WG/CU (lstm isolation, R13/R14-proven).
// syncp[0] = gemm done counter; syncp[16+bid*16] = per-lstm-WG progress.
// ---------------------------------------------------------------------------
#define GEMM_WGS 6144
#define ATTN_WGS 2432
__global__ __launch_bounds__(256, 1) void mega(
    const unsigned short* __restrict__ xg,   // [t][jg32][b][c]  c = gate*16+hl
    const unsigned short* __restrict__ Whh,  // (2048, 512) bf16
    unsigned short* __restrict__ h_all,      // [b][t][h]  (128, 512, 512)
    unsigned int* __restrict__ ring,         // [2][128][512] tagged words
    const unsigned short* __restrict__ x_bf,
    const unsigned short* __restrict__ Wih_bf,
    const float* __restrict__ bias,
    unsigned short* __restrict__ xg_out,
    int* __restrict__ syncp,
    const unsigned short* __restrict__ U1a,
    const unsigned short* __restrict__ U2b)
{
    __shared__ __align__(16) char smem[86016];   // forces 1 WG/CU for all roles

    const int tid = threadIdx.x;

    if (blockIdx.x >= 64 && blockIdx.x < 64 + GEMM_WGS) {
        // ---------------- xg GEMM role: t in [128,512) ----------------
        int g = blockIdx.x - 64;
        int b = g & 127;
        int r = g >> 7;                  // 0..47
        int ti = 1 + (r % 3);            // 1..3
        int n = r / 3;                   // 0..15
        gemm_core(x_bf, 512, Wih_bf, 512, xg_out, 2048, bias, 1,
                  b * 512 + ti * 128, n * 128, tid, (unsigned short*)smem);
        __syncthreads();                 // all waves' stores drained
        if (tid == 0)
            __hip_atomic_fetch_add(&syncp[0], 1, __ATOMIC_RELEASE,
                                   __HIP_MEMORY_SCOPE_AGENT);
        return;
    }

    if (blockIdx.x >= 64 + GEMM_WGS) {
        // ------------- attn helper role: a = h@U1a^T + x@U2^T -------------
        const int g = blockIdx.x - 64 - GEMM_WGS;
        if (g < 1920) {
            attn_helper_body<8>(h_all, x_bf, U1a, U2b, xg_out, syncp,
                                g & 127, (g >> 7) * 32, 0, tid, smem);
        } else {
            const int j = g - 1920;
            attn_helper_body<2>(h_all, x_bf, U1a, U2b, xg_out, syncp,
                                j & 127, 480, (j >> 7) * 128, tid, smem);
        }
        return;
    }

    // ---------------- lstm role (R14 VERBATIM inner loop) ----------------
    // XCD-grouped derivation: the 8 exchange partners of bg-group `bg` are
    // bids {bg, 8+bg, ..., 56+bg} -> all share bid%8 -> same XCD under the
    // observed round-robin dispatch map. Pure locality heuristic; the
    // agent-scope ring protocol is placement-independent.
    unsigned int (*At)[16 * 264] = (unsigned int (*)[16 * 264])smem;

    const int wv = tid >> 6, lane = tid & 63, l15 = lane & 15, q = lane >> 4;
    const int bg = (int)blockIdx.x & 7, jgb = (int)blockIdx.x >> 3;
    const int b0 = bg * 16;
    const int jg32 = jgb * 4 + wv;            // 16-hid group of this wave
    const int hid = jg32 * 16 + l15;          // this lane's hidden index

    // W_hh B-frags: Wreg[ct][kk], row = ct*512 + hid, k = kk*32 + q*8
    short8 Wreg[4][16];
    #pragma unroll
    for (int ct = 0; ct < 4; ct++)
        #pragma unroll
        for (int kk = 0; kk < 16; kk++)
            Wreg[ct][kk] = *(const short8*)
                &Whh[(long long)(ct * 512 + hid) * 512 + kk * 32 + q * 8];

    float cst[4] = {0.f, 0.f, 0.f, 0.f};

    for (int t = 0; t < 512; t++) {
        // one-time guard: xg[t>=128] is produced by the gemm role
        if (t == 128) {
            if (tid == 0) {
                while (__hip_atomic_load(&syncp[0], __ATOMIC_ACQUIRE,
                                         __HIP_MEMORY_SCOPE_AGENT) < GEMM_WGS)
                    __builtin_amdgcn_s_sleep(8);
            }
            __syncthreads();
        }
        // ---- prefetch xg: acc-init values, 16 scalar loads (pre-poll) ----
        const long long xbase = ((long long)(t * 32 + jg32) * 128 + b0) * 64;
        floatx4 acc[4];
        #pragma unroll
        for (int ct = 0; ct < 4; ct++)
            #pragma unroll
            for (int r = 0; r < 4; r++)
                acc[ct][r] = b2f(xg[xbase + (q * 4 + r) * 64 + ct * 16 + l15]);

        if (t > 0) {
            const unsigned want = (unsigned)(t - 1);
            const int sl = (t - 1) & 1;
            unsigned long long* rb = (unsigned long long*)
                (ring + sl * 65536 + b0 * 512);
            unsigned long long w[16];
            #pragma unroll
            for (int i = 0; i < 16; i++)
                w[i] = __hip_atomic_load(&rb[tid + i * 256], __ATOMIC_RELAXED,
                                         __HIP_MEMORY_SCOPE_AGENT);
            while (true) {
                unsigned bad = 0;
                #pragma unroll
                for (int i = 0; i < 16; i++) {
                    unsigned lo = (unsigned)(w[i] >> 16) & 0xFFFFu;
                    unsigned hi = (unsigned)(w[i] >> 48);
                    bad |= (lo ^ want) | (hi ^ want);
                }
                if (!bad) break;
                #pragma unroll
                for (int i = 0; i < 16; i++) {
                    unsigned lo = (unsigned)(w[i] >> 16) & 0xFFFFu;
                    unsigned hi = (unsigned)(w[i] >> 48);
                    if ((lo ^ want) | (hi ^ want))
                        w[i] = __hip_atomic_load(&rb[tid + i * 256], __ATOMIC_RELAXED,
                                                 __HIP_MEMORY_SCOPE_AGENT);
                }
            }
            // strip tags, pack two bf16 per LDS word
            unsigned int* dst = &At[sl][0];
            #pragma unroll
            for (int i = 0; i < 16; i++) {
                int idx = tid + i * 256;
                int row = idx >> 8, k = idx & 255;
                dst[row * 264 + k] =
                    (unsigned)(w[i] & 0xFFFFu) | ((unsigned)(w[i] >> 32) << 16);
            }
            __syncthreads();
            // MFMA: A = h tile (batch l15, K), B = Wreg; 4 chains (one/gate)
            const unsigned int* ap = &At[sl][l15 * 264 + q * 4];
            #pragma unroll
            for (int kk = 0; kk < 16; kk++) {
                short8 af = *(const short8*)(ap + kk * 16);
                acc[0] = MFMA16(af, Wreg[0][kk], acc[0]);
                acc[1] = MFMA16(af, Wreg[1][kk], acc[1]);
                acc[2] = MFMA16(af, Wreg[2][kk], acc[2]);
                acc[3] = MFMA16(af, Wreg[3][kk], acc[3]);
            }
        }
        // ---- pointwise: gates are in-lane (acc[0..3] = i,f,g,o) ----
        unsigned short hbv[4];
        #pragma unroll
        for (int r = 0; r < 4; r++) {
            float ig = sigm(acc[0][r]);
            float fg = sigm(acc[1][r]);
            float gv = tanh_(acc[2][r]);
            float og = sigm(acc[3][r]);
            cst[r] = fg * cst[r] + ig * gv;
            hbv[r] = f2b(og * tanh_(cst[r]));
        }
        // publish: ring first (latency-critical)
        #pragma unroll
        for (int r = 0; r < 4; r++) {
            const int b = b0 + q * 4 + r;
            __hip_atomic_store(&ring[(t & 1) * 65536 + b * 512 + hid],
                               ((unsigned)t << 16) | hbv[r], __ATOMIC_RELAXED,
                               __HIP_MEMORY_SCOPE_AGENT);
        }
        // h_all: agent-visible packed 4B atomic stores (pair hid, hid^1)
        // so shadow helpers' LLC-direct atomic loads always see fresh data.
        #pragma unroll
        for (int r = 0; r < 4; r++) {
            const int b = b0 + q * 4 + r;
            int o = __shfl_xor((int)hbv[r], 1);
            if (!(l15 & 1)) {
                unsigned v = (unsigned)hbv[r] | (((unsigned)(unsigned short)o) << 16);
                __hip_atomic_store(
                    (unsigned*)&h_all[(long long)b * 262144 + (long long)t * 512 + hid],
                    v, __ATOMIC_RELAXED, __HIP_MEMORY_SCOPE_AGENT);
            }
        }
        // progress word every 16 steps: barrier drains all waves' h stores
        // (agent-visible), so prog >= t+1 implies h[..t] readable by helpers.
        if ((t & 15) == 15) {
            __syncthreads();
            if (tid == 0)
                __hip_atomic_store(&syncp[16 + (int)blockIdx.x * 16], t + 1,
                                   __ATOMIC_RELAXED, __HIP_MEMORY_SCOPE_AGENT);
        }
    }
}

// ---------------------------------------------------------------------------
// attn_out: u1b = h_last@U1b^T (in-WG), e = Ve.tanh(a + u1b) (a from xg
// slots), softmax over T, context = alpha.h, head -> mu, sigma. 1 WG per b.
// ---------------------------------------------------------------------------
__global__ __launch_bounds__(256) void attn_out(
    const unsigned short* __restrict__ a_xg,  // fp32 a[] in xg slot layout
    const unsigned short* __restrict__ h_all,
    const unsigned short* __restrict__ U1b,   // bf16 (512,512)
    const float* __restrict__ Ve,
    const float* __restrict__ Wout, const float* __restrict__ bout,
    float* __restrict__ outp)
{
    __shared__ float hl[512];
    __shared__ float u1s[512];
    __shared__ float se[512];
    __shared__ float sm[512];
    __shared__ float red[8];
    const int b = blockIdx.x, tid = threadIdx.x;
    const int wv = tid >> 6, lane = tid & 63;

    // ---- phase 0: u1b[b,n] = sum_k h_last[b,k] * U1b[n,k] ----
    {
        unsigned v = ((const unsigned*)(h_all + (long long)b * 262144 + 511LL * 512))[tid];
        hl[2 * tid]     = b2f((unsigned short)(v & 0xFFFFu));
        hl[2 * tid + 1] = b2f((unsigned short)(v >> 16));
    }
    __syncthreads();
    #pragma unroll
    for (int rr = 0; rr < 2; rr++) {
        const int n = tid + rr * 256;
        const unsigned short* up = &U1b[(long long)n * 512];
        float s = 0.f;
        for (int k = 0; k < 512; k += 8) {
            short8 v8 = *(const short8*)&up[k];
            #pragma unroll
            for (int j = 0; j < 8; j++)
                s += hl[k + j] * b2f((unsigned short)v8[j]);
        }
        u1s[n] = s;
    }
    __syncthreads();

    // ---- phase 1: e[t] = sum_n Ve[n] * tanh(a[t,n] + u1b[b,n]) ----
    const int n0 = lane * 8;
    float ve[8], ub[8];
    #pragma unroll
    for (int j = 0; j < 8; j++) {
        ve[j] = Ve[n0 + j];
        ub[j] = u1s[n0 + j];
    }
    for (int it = 0; it < 64; it++) {
        const int t = it * 8 + wv * 2;
        const float* s0p = (const float*)
            &a_xg[(((long long)t * 32 + (n0 >> 5)) * 128 + b) * 64];
        const float* s1p = (const float*)
            &a_xg[(((long long)(t + 1) * 32 + (n0 >> 5)) * 128 + b) * 64];
        float4 a0 = *(const float4*)&s0p[n0 & 31];
        float4 a1 = *(const float4*)&s0p[(n0 & 31) + 4];
        float4 a2 = *(const float4*)&s1p[n0 & 31];
        float4 a3 = *(const float4*)&s1p[(n0 & 31) + 4];
        float s0 = ve[0] * tanh_(a0.x + ub[0]) + ve[1] * tanh_(a0.y + ub[1])
                 + ve[2] * tanh_(a0.z + ub[2]) + ve[3] * tanh_(a0.w + ub[3])
                 + ve[4] * tanh_(a1.x + ub[4]) + ve[5] * tanh_(a1.y + ub[5])
                 + ve[6] * tanh_(a1.z + ub[6]) + ve[7] * tanh_(a1.w + ub[7]);
        float s1 = ve[0] * tanh_(a2.x + ub[0]) + ve[1] * tanh_(a2.y + ub[1])
                 + ve[2] * tanh_(a2.z + ub[2]) + ve[3] * tanh_(a2.w + ub[3])
                 + ve[4] * tanh_(a3.x + ub[4]) + ve[5] * tanh_(a3.y + ub[5])
                 + ve[6] * tanh_(a3.z + ub[6]) + ve[7] * tanh_(a3.w + ub[7]);
        #pragma unroll
        for (int off = 1; off <= 32; off <<= 1) {
            s0 += __shfl_xor(s0, off);
            s1 += __shfl_xor(s1, off);
        }
        if (lane == 0) { se[t] = s0; se[t + 1] = s1; }
    }
    __syncthreads();

    // ---- phase 2: softmax over T ----
    float e0 = se[tid], e1 = se[256 + tid];
    float mx = fmaxf(e0, e1);
    for (int off = 32; off; off >>= 1) mx = fmaxf(mx, __shfl_xor(mx, off));
    if (lane == 0) red[wv] = mx;
    __syncthreads();
    mx = fmaxf(fmaxf(red[0], red[1]), fmaxf(red[2], red[3]));

    float s0 = __expf(e0 - mx), s1 = __expf(e1 - mx);
    sm[tid] = s0; sm[256 + tid] = s1;
    float ss = s0 + s1;
    for (int off = 32; off; off >>= 1) ss += __shfl_xor(ss, off);
    if (lane == 0) red[4 + wv] = ss;
    __syncthreads();
    float inv = 1.0f / (red[4] + red[5] + red[6] + red[7]);

    // ---- phase 3: context = alpha.h, head ----
    const unsigned int* hp = (const unsigned int*)(h_all + (long long)b * 262144);
    float a0 = 0.f, a1 = 0.f;
    for (int t = 0; t < 512; t += 4) {
        #pragma unroll
        for (int j = 0; j < 4; j++) {
            float al = sm[t + j];
            unsigned v = hp[(t + j) * 256 + tid];
            a0 += al * b2f((unsigned short)(v & 0xFFFFu));
            a1 += al * b2f((unsigned short)(v >> 16));
        }
    }
    a0 *= inv; a1 *= inv;

    float q0 = a0 * Wout[2 * tid] + a1 * Wout[2 * tid + 1];
    float q1 = a0 * Wout[512 + 2 * tid] + a1 * Wout[512 + 2 * tid + 1];
    for (int off = 32; off; off >>= 1) { q0 += __shfl_xor(q0, off); q1 += __shfl_xor(q1, off); }
    __syncthreads();  // red reuse
    if (lane == 0) { red[wv] = q0; red[4 + wv] = q1; }
    __syncthreads();
    if (tid == 0) {
        float P0 = red[0] + red[1] + red[2] + red[3] + bout[0];
        float P1 = red[4] + red[5] + red[6] + red[7] + bout[1];
        outp[b] = P0;
        float sp = (P1 > 15.0f) ? P1 : log1pf(__expf(P1));
        outp[128 + b] = sp + 1e-5f;
    }
}

// ---------------------------------------------------------------------------
extern "C" void kernel_launch(void* const* d_in, const int* in_sizes, int n_in,
                              void* d_out, int out_size, void* d_ws, size_t ws_size,
                              hipStream_t stream)
{
    const float* x    = (const float*)d_in[0];
    const float* Wih  = (const float*)d_in[1];
    const float* Whh  = (const float*)d_in[2];
    const float* bih  = (const float*)d_in[3];
    const float* bhh  = (const float*)d_in[4];
    const float* Ve   = (const float*)d_in[5];
    const float* U1   = (const float*)d_in[6];
    const float* U2   = (const float*)d_in[7];
    const float* Wout = (const float*)d_in[8];
    const float* bout = (const float*)d_in[9];
    float* out = (float*)d_out;

    char* ws = (char*)d_ws;
    size_t off = 0;
    auto alloc = [&](size_t bytes) -> void* {
        void* p = ws + off;
        off += (bytes + 255) & ~(size_t)255;
        return p;
    };
    unsigned short* x_bf   = (unsigned short*)alloc(33554432ull * 2);
    unsigned short* Wih_bf = (unsigned short*)alloc(1048576ull * 2);
    unsigned short* Whh_bf = (unsigned short*)alloc(1048576ull * 2);
    unsigned short* U1a    = (unsigned short*)alloc(262144ull * 2);
    unsigned short* U1b    = (unsigned short*)alloc(262144ull * 2);
    unsigned short* U2b    = (unsigned short*)alloc(262144ull * 2);
    float*          bias   = (float*)alloc(2048ull * 4);
    unsigned short* xg     = (unsigned short*)alloc(134217728ull * 2);
    unsigned short* h_all  = (unsigned short*)alloc(33554432ull * 2);
    unsigned int*   ring   = (unsigned int*)alloc(131072ull * 4);  // 2x128x512 tagged
    int*            syncp  = (int*)alloc(8192ull);  // [0]=gemm done; [16+wg*16]=prog
    if (off > ws_size) return;  // workspace too small: fail safe (no corruption)

    hipMemsetAsync(syncp, 0, 8192, stream);
    prep<<<4096, 256, 0, stream>>>(x, Wih, Whh, bih, bhh, U1, U2,
                                   x_bf, Wih_bf, Whh_bf, U1a, U1b, U2b, bias);
    // xg for t<128 only (ti=0): m0 = b*512, 2048 WGs
    gemm_bt<<<dim3(128, 16), 256, 0, stream>>>(x_bf, 512, Wih_bf, 512,
                                               xg, 2048, bias, 1, 512);
    // mega: 64 lstm + 6144 xg-gemm (t in [128,512)) + 2432 attn helpers
    mega<<<64 + GEMM_WGS + ATTN_WGS, 256, 0, stream>>>(
        xg, Whh_bf, h_all, ring, x_bf, Wih_bf, bias, xg, syncp, U1a, U2b);
    attn_out<<<128, 256, 0, stream>>>(xg, h_all, U1b, Ve, Wout, bout, out);
}